// Round 7
// baseline (317.260 us; speedup 1.0000x reference)
//
#include <hip/hip_runtime.h>

// TvarLayer: out[b, (n*C+c)*9+k, l] = (p_k*W[n,c,k] - mean_k(p*W))^2 / sum_k(W[n,c,k]) + Bbias[n,c]
// B=4, N=8, C=8, K=9 (3x3, pad 1, stride 1), H=W=128, L=16384. Out 151 MB f32.
//
// R2: n split across blocks (4096 blocks)          -> NEUTRAL (kernel ~63us)
// R5: NT stores -> cached stores                   -> small win (~59us); fill proves 6.35 TB/s
// R6: THEORY B test: one block per output PLANE (b,n,c,k) = 2304 blocks; each block
//     writes its 64KB plane fully contiguously (4KB dense per iteration) instead of
//     9 x 4KB chunks at 64KB stride. Input re-read x9 is L2-resident (2MB), mean
//     recompute x9 costs ~8.6us aggregate VALU vs 24us memory floor.

#define BB 4
#define NN 8
#define CC 8
#define KK 9
#define HH 128
#define WW 128
#define LL (HH * WW)

typedef float vf4 __attribute__((ext_vector_type(4)));

__global__ __launch_bounds__(256) void tvar_kernel(
    const float* __restrict__ arr,
    const float* __restrict__ Wt,
    const float* __restrict__ Bb,
    float* __restrict__ out)
{
    // grid: x = k (0..8), y = n*8+c (0..63), z = b (0..3)
    const int k  = blockIdx.x;
    const int nc = blockIdx.y;
    const int b  = blockIdx.z;
    const int c  = nc & 7;

    const int t  = threadIdx.x;
    const int w4 = t & 31;
    const int hb = t >> 5;          // 0..7
    const int ws = w4 << 2;

    // block-uniform weights -> scalar loads
    const float* wrow = Wt + nc * KK;
    float w9[KK];
    float wsum = 0.f;
    #pragma unroll
    for (int kk = 0; kk < KK; ++kk) { w9[kk] = wrow[kk]; wsum += w9[kk]; }
    const float sinv = 1.0f / wsum;
    const float bias = Bb[nc];
    const float wk   = w9[k];
    const int kh = k / 3, kw = k - kh * 3;   // block-uniform
    const float inv9 = 1.0f / 9.0f;

    const float* abase = arr + (size_t)((b * CC + c) * HH) * WW;
    float* oplane = out + ((size_t)(b * (NN * CC) + nc) * KK + k) * LL;

    #pragma unroll 2
    for (int i = 0; i < 16; ++i) {
        const int h = (i << 3) | hb;

        // 3x6 zero-padded patch around (h, ws-1..ws+4)
        float p[3][6];
        #pragma unroll
        for (int r = 0; r < 3; ++r) {
            const int hh = h + r - 1;
            if (hh >= 0 && hh < HH) {
                const float* row = abase + hh * WW + ws;
                const float4 v = *(const float4*)row;      // 16B-aligned
                p[r][1] = v.x; p[r][2] = v.y; p[r][3] = v.z; p[r][4] = v.w;
                p[r][0] = (ws > 0)      ? row[-1] : 0.f;
                p[r][5] = (ws + 4 < WW) ? row[4]  : 0.f;
            } else {
                #pragma unroll
                for (int j = 0; j < 6; ++j) p[r][j] = 0.f;
            }
        }

        float mean[4] = {0.f, 0.f, 0.f, 0.f};
        #pragma unroll
        for (int kk = 0; kk < KK; ++kk) {
            const int rh = kk / 3, rw = kk - rh * 3;
            #pragma unroll
            for (int j = 0; j < 4; ++j)
                mean[j] += p[rh][j + rw] * w9[kk];
        }

        vf4 o;
        #pragma unroll
        for (int j = 0; j < 4; ++j) {
            const float v = p[kh][j + kw] * wk;
            const float d = v - mean[j] * inv9;
            o[j] = d * d * sinv + bias;
        }
        // block writes 4KB dense per iteration, marching sequentially through
        // its 64KB plane -> chip-wide write stream is dense like the 6.35 TB/s fill
        *(vf4*)(oplane + h * WW + ws) = o;
    }
}

extern "C" void kernel_launch(void* const* d_in, const int* in_sizes, int n_in,
                              void* d_out, int out_size, void* d_ws, size_t ws_size,
                              hipStream_t stream) {
    const float* arr = (const float*)d_in[0];
    const float* Wt  = (const float*)d_in[1];
    const float* Bb  = (const float*)d_in[2];
    float* out = (float*)d_out;

    dim3 grid(KK, NN * CC, BB);   // 9 * 64 * 4 = 2304 blocks, one 64KB plane each
    tvar_kernel<<<grid, 256, 0, stream>>>(arr, Wt, Bb, out);
}

// Round 9
// 157.012 us; speedup vs baseline: 2.0206x; 2.0206x over previous
//
#include <hip/hip_runtime.h>

// TvarLayer: out[b, (n*C+c)*9+k, l] = (p_k*W[n,c,k] - mean_k(p*W))^2 / sum_k(W[n,c,k]) + Bbias[n,c]
// B=4, N=8, C=8, K=9 (3x3, pad 1, stride 1), H=W=128, L=16384. Out 151 MB f32.
//
// R2: n split across blocks (4096 blocks)  -> NEUTRAL
// R5: NT -> cached stores                  -> ~59us kernel (inferred); best so far
// R7: plane-per-block                      -> 200us, WRITE_SIZE 718 MiB = 5x output (!!)
// R8: INSTRUMENTATION ROUND. R5 kernel, store phase executed TWICE (pass 0 garbage,
//     pass 1 correct; asm pointer-escape defeats DSE). Pushes kernel >97us so its
//     counter row appears in top-5: resolves (a) true R5 kernel time (dur/2-ish),
//     (b) whether the R5 write pattern amplifies EA writes (WRITE_SIZE vs 295k KB).

#define BB 4
#define NN 8
#define CC 8
#define KK 9
#define HH 128
#define WW 128
#define LL (HH * WW)

typedef float vf4 __attribute__((ext_vector_type(4)));

__global__ __launch_bounds__(256) void tvar_kernel(
    const float* __restrict__ arr,
    const float* __restrict__ Wt,
    const float* __restrict__ Bb,
    float* __restrict__ out)
{
    // block: bid = b(2) | n(3) | c(3) | hi(4);  thread: hlo(3) | w4(5)
    const int bid = blockIdx.x;
    const int hi = bid & 15;
    const int c  = (bid >> 4) & 7;
    const int n  = (bid >> 7) & 7;
    const int b  = bid >> 10;

    const int lt = threadIdx.x;
    const int w4 = lt & 31;
    const int h  = (hi << 3) | (lt >> 5);

    // block-uniform -> scalar loads
    const float* wrow = Wt + (n * CC + c) * KK;
    float w9[KK];
    float wsum = 0.f;
    #pragma unroll
    for (int k = 0; k < KK; ++k) { w9[k] = wrow[k]; wsum += w9[k]; }
    const float sinv = 1.0f / wsum;
    const float bias = Bb[n * CC + c];

    // Load 3x6 patch (rows h-1..h+1, cols ws-1..ws+4), zero-padded.
    const int ws = w4 << 2;
    const float* abase = arr + (size_t)((b * CC + c) * HH) * WW;
    float p[3][6];
    #pragma unroll
    for (int r = 0; r < 3; ++r) {
        const int hh = h + r - 1;
        if (hh >= 0 && hh < HH) {
            const float* row = abase + hh * WW + ws;
            const float4 v = *(const float4*)row;          // ws is 16B-aligned
            p[r][1] = v.x; p[r][2] = v.y; p[r][3] = v.z; p[r][4] = v.w;
            p[r][0] = (ws > 0)      ? row[-1] : 0.f;
            p[r][5] = (ws + 4 < WW) ? row[4]  : 0.f;
        } else {
            #pragma unroll
            for (int j = 0; j < 6; ++j) p[r][j] = 0.f;
        }
    }

    const float inv9 = 1.0f / 9.0f;
    float mean[4] = {0.f, 0.f, 0.f, 0.f};
    #pragma unroll
    for (int k = 0; k < KK; ++k) {
        const int kh = k / 3, kw = k - kh * 3;
        #pragma unroll
        for (int j = 0; j < 4; ++j)
            mean[j] += p[kh][j + kw] * w9[k];
    }
    #pragma unroll
    for (int j = 0; j < 4; ++j) mean[j] *= inv9;

    float* onb = out + (size_t)b * (NN * CC * KK) * LL
                     + (size_t)((n * CC + c) * KK) * LL
                     + (size_t)(h * WW + ws);

    // === instrumented double-write: pass 0 garbage, pass 1 correct values ===
    for (int rep = 0; rep < 2; ++rep) {
        const float junk = (rep == 0) ? 1.2345f : 0.0f;
        float* op = onb;
        // opaque pointer: compiler cannot prove pass-0 stores dead
        asm volatile("" : "+v"(op));
        #pragma unroll
        for (int k = 0; k < KK; ++k) {
            const int kh = k / 3, kw = k - kh * 3;
            vf4 o;
            #pragma unroll
            for (int j = 0; j < 4; ++j) {
                const float v = p[kh][j + kw] * w9[k];
                const float d = v - mean[j];
                o[j] = d * d * sinv + bias + junk;
            }
            *(vf4*)(op + (size_t)k * LL) = o;
        }
        asm volatile("" ::: "memory");
    }
}

extern "C" void kernel_launch(void* const* d_in, const int* in_sizes, int n_in,
                              void* d_out, int out_size, void* d_ws, size_t ws_size,
                              hipStream_t stream) {
    const float* arr = (const float*)d_in[0];
    const float* Wt  = (const float*)d_in[1];
    const float* Bb  = (const float*)d_in[2];
    float* out = (float*)d_out;

    // threads total = B*N*C*H*(W/4) = 4*8*8*128*32 = 1,048,576 -> 4096 blocks
    const int threads = 256;
    const int blocks = BB * NN * CC * 16;  // 4096
    tvar_kernel<<<blocks, threads, 0, stream>>>(arr, Wt, Bb, out);
}

// Round 10
// 154.420 us; speedup vs baseline: 2.0545x; 1.0168x over previous
//
#include <hip/hip_runtime.h>

// TvarLayer: out[b, (n*C+c)*9+k, l] = (p_k*W[n,c,k] - mean_k(p*W))^2 / sum_k(W[n,c,k]) + Bbias[n,c]
// B=4, N=8, C=8, K=9 (3x3, pad 1, stride 1), H=W=128, L=16384. Out 151 MB f32.
//
// Ledger (JSON dur = kernel + ~91us poison fill + ~26us misc; anchored by R7's 200us row):
//   R2 occupancy x8      -> NEUTRAL   (kernel ~41us)
//   R5 NT -> cached      -> ~37us kernel; 4.4 TB/s vs fill's 6.3
//   R7 plane-per-block   -> 200us, WRITE_SIZE 5x (pathological)
//   R9 double-write      -> +2.6us only: L2 merged the pair => bound beyond L2
// R10: XCD-sharded writes. bid%8 = XCD (m09); each XCD gets one contiguous 18 MiB
//      output shard (32 consecutive (b,nc) pairs) so each XCD-L2 drains a single
//      dense address window to HBM. Only the bid->(b,nc,hi) map changes vs R5.

#define BB 4
#define NN 8
#define CC 8
#define KK 9
#define HH 128
#define WW 128
#define LL (HH * WW)

typedef float vf4 __attribute__((ext_vector_type(4)));

__global__ __launch_bounds__(256) void tvar_kernel(
    const float* __restrict__ arr,
    const float* __restrict__ Wt,
    const float* __restrict__ Bb,
    float* __restrict__ out)
{
    // XCD-sharded decomposition: xcd = bid&7 (dispatch round-robins XCDs),
    // shard x owns (b*64+nc) in [x*32, x*32+32) = 18 MiB of contiguous output.
    const int bid = blockIdx.x;            // 0..4095
    const int xcd = bid & 7;
    const int j   = bid >> 3;              // 0..511
    const int bnc = (xcd << 5) | (j & 31); // b*64+nc, contiguous per XCD
    const int hi  = j >> 5;                // 0..15
    const int nc  = bnc & 63;
    const int b   = bnc >> 6;
    const int c   = nc & 7;

    const int lt = threadIdx.x;
    const int w4 = lt & 31;
    const int h  = (hi << 3) | (lt >> 5);

    // block-uniform -> scalar loads
    const float* wrow = Wt + nc * KK;
    float w9[KK];
    float wsum = 0.f;
    #pragma unroll
    for (int k = 0; k < KK; ++k) { w9[k] = wrow[k]; wsum += w9[k]; }
    const float sinv = 1.0f / wsum;
    const float bias = Bb[nc];

    // Load 3x6 patch (rows h-1..h+1, cols ws-1..ws+4), zero-padded.
    const int ws = w4 << 2;
    const float* abase = arr + (size_t)((b * CC + c) * HH) * WW;
    float p[3][6];
    #pragma unroll
    for (int r = 0; r < 3; ++r) {
        const int hh = h + r - 1;
        if (hh >= 0 && hh < HH) {
            const float* row = abase + hh * WW + ws;
            const float4 v = *(const float4*)row;          // ws is 16B-aligned
            p[r][1] = v.x; p[r][2] = v.y; p[r][3] = v.z; p[r][4] = v.w;
            p[r][0] = (ws > 0)      ? row[-1] : 0.f;
            p[r][5] = (ws + 4 < WW) ? row[4]  : 0.f;
        } else {
            #pragma unroll
            for (int j2 = 0; j2 < 6; ++j2) p[r][j2] = 0.f;
        }
    }

    const float inv9 = 1.0f / 9.0f;
    float mean[4] = {0.f, 0.f, 0.f, 0.f};
    #pragma unroll
    for (int k = 0; k < KK; ++k) {
        const int kh = k / 3, kw = k - kh * 3;
        #pragma unroll
        for (int j2 = 0; j2 < 4; ++j2)
            mean[j2] += p[kh][j2 + kw] * w9[k];
    }
    #pragma unroll
    for (int j2 = 0; j2 < 4; ++j2) mean[j2] *= inv9;

    float* onb = out + (size_t)bnc * KK * LL + (size_t)(h * WW + ws);
    #pragma unroll
    for (int k = 0; k < KK; ++k) {
        const int kh = k / 3, kw = k - kh * 3;
        vf4 o;
        #pragma unroll
        for (int j2 = 0; j2 < 4; ++j2) {
            const float v = p[kh][j2 + kw] * w9[k];
            const float d = v - mean[j2];
            o[j2] = d * d * sinv + bias;
        }
        *(vf4*)(onb + (size_t)k * LL) = o;
    }
}

extern "C" void kernel_launch(void* const* d_in, const int* in_sizes, int n_in,
                              void* d_out, int out_size, void* d_ws, size_t ws_size,
                              hipStream_t stream) {
    const float* arr = (const float*)d_in[0];
    const float* Wt  = (const float*)d_in[1];
    const float* Bb  = (const float*)d_in[2];
    float* out = (float*)d_out;

    // threads total = B*N*C*H*(W/4) = 4*8*8*128*32 = 1,048,576 -> 4096 blocks
    const int threads = 256;
    const int blocks = BB * NN * CC * 16;  // 4096
    tvar_kernel<<<blocks, threads, 0, stream>>>(arr, Wt, Bb, out);
}